// Round 3
// baseline (36.279 us; speedup 1.0000x reference)
//
#include <hip/hip_runtime.h>

constexpr int PP = 16;       // patch
constexpr int NSEL = 128;    // N
constexpr int B = 4, C = 3, H = 256, W = 256;
constexpr int L = 256;       // patches per batch (16x16)
constexpr int TPB = 256;
constexpr int GBLK = 160;    // one dispatch: 4 selection blocks are blocks 0..3
constexpr int XQ = B * NSEL * (C * PP * PP) / 4;   // 98304 float4s (x_sample)
constexpr int TOTAL_F4 = XQ + B * NSEL * 512 / 4;  // 163840 float4s
constexpr unsigned long long MAGIC = 0x5EC7ED21C0FFEE42ull;

__device__ __forceinline__ unsigned rotl32(unsigned x, int d) {
  return (x << d) | (x >> (32 - d));
}

// Threefry-2x32, 20 rounds (Random123 / JAX), key=(0,42), partitionable mode:
// counter=(0, i), bits = y0 ^ y1. Verified exact (absmax 0.0, rounds 1-2).
__device__ __forceinline__ void threefry2x32(unsigned k0, unsigned k1,
                                             unsigned& x0, unsigned& x1) {
  unsigned ks[3] = {k0, k1, k0 ^ k1 ^ 0x1BD11BDAu};
  x0 += ks[0];
  x1 += ks[1];
  const int rot[2][4] = {{13, 15, 26, 6}, {17, 29, 16, 24}};
#pragma unroll
  for (int i = 0; i < 5; ++i) {
    const int* r = rot[i & 1];
#pragma unroll
    for (int j = 0; j < 4; ++j) {
      x0 += x1;
      x1 = rotl32(x1, r[j]);
      x1 ^= x0;
    }
    x0 += ks[(i + 1) % 3];
    x1 += ks[(i + 2) % 3] + (unsigned)(i + 1);
  }
}

// Single fused dispatch.
//  Blocks 0..3: per-batch selection (mask-patch sums -> threefry monotone
//  score -> stable rank -> ballot compaction), publish idx + release MAGIC.
//  All blocks: wave-poll the 4 flags, then gather 4 float4s per thread.
// Poison-safe doorbell: 0xAA.. != MAGIC forces handshake on first replay;
// later replays may read the previous replay's idx, which is bit-identical.
__global__ __launch_bounds__(TPB) void fused_kernel(
    const float* __restrict__ x, const float* __restrict__ mask,
    const float* __restrict__ pos, float4* __restrict__ out,
    int* __restrict__ ws) {
  int* idx = ws;                                                  // 512 ints
  unsigned long long* flags = (unsigned long long*)(ws + 512);    // 4 x u64
  const int blk = blockIdx.x;
  const int l = threadIdx.x;

  if (blk < B) {
    // ---- selection for batch blk ----
    const int b = blk;
    int ri = (l >> 4) << 4, ci = (l & 15) << 4;
    const float* base = mask + ((size_t)b * H + ri) * W + ci;
    float s = 0.0f;
#pragma unroll
    for (int r = 0; r < PP; ++r) {
#pragma unroll
      for (int c4 = 0; c4 < 4; ++c4) {
        const float4 v =
            *reinterpret_cast<const float4*>(base + r * W + c4 * 4);
        s += v.x + v.y + v.z + v.w;
      }
    }
    bool valid = (s * (1.0f / 256.0f)) >= 1.0f;

    unsigned x0 = 0u, x1 = (unsigned)(b * L + l);
    threefry2x32(0u, 42u, x0, x1);
    unsigned score = valid ? (((x0 ^ x1) >> 9) + 1u) : 0u;

    __shared__ unsigned s_score[L];
    __shared__ int s_wcnt[4];
    s_score[l] = score;
    __syncthreads();

    int rank = 0;
    const uint4* sv = reinterpret_cast<const uint4*>(s_score);
#pragma unroll 8
    for (int m4 = 0; m4 < L / 4; ++m4) {
      uint4 v = sv[m4];
      int m = m4 << 2;
      rank += (v.x > score) || (v.x == score && (m + 0) < l);
      rank += (v.y > score) || (v.y == score && (m + 1) < l);
      rank += (v.z > score) || (v.z == score && (m + 2) < l);
      rank += (v.w > score) || (v.w == score && (m + 3) < l);
    }
    bool sel = rank < NSEL;

    unsigned long long mb = __ballot(sel);
    int w = l >> 6, ln = l & 63;
    if (ln == 0) s_wcnt[w] = __popcll(mb);
    __syncthreads();
    int slot = __popcll(mb & ((1ull << ln) - 1ull));
#pragma unroll
    for (int j = 0; j < 4; ++j) slot += (j < w) ? s_wcnt[j] : 0;
    if (sel)
      __hip_atomic_store(&idx[b * NSEL + slot], l, __ATOMIC_RELAXED,
                         __HIP_MEMORY_SCOPE_AGENT);
    __syncthreads();
    if (l == 0) {
      __threadfence();  // agent fence: idx stores visible before doorbell
      __hip_atomic_store(&flags[b], MAGIC, __ATOMIC_RELEASE,
                         __HIP_MEMORY_SCOPE_AGENT);
    }
  }

  // ---- wave-level doorbell poll (lane 0 per wave; lanes are lockstep) ----
  if ((l & 63) == 0) {
    while (true) {
      unsigned long long f0 = __hip_atomic_load(&flags[0], __ATOMIC_ACQUIRE,
                                                __HIP_MEMORY_SCOPE_AGENT);
      unsigned long long f1 = __hip_atomic_load(&flags[1], __ATOMIC_ACQUIRE,
                                                __HIP_MEMORY_SCOPE_AGENT);
      unsigned long long f2 = __hip_atomic_load(&flags[2], __ATOMIC_ACQUIRE,
                                                __HIP_MEMORY_SCOPE_AGENT);
      unsigned long long f3 = __hip_atomic_load(&flags[3], __ATOMIC_ACQUIRE,
                                                __HIP_MEMORY_SCOPE_AGENT);
      if (f0 == MAGIC && f1 == MAGIC && f2 == MAGIC && f3 == MAGIC) break;
      __builtin_amdgcn_s_sleep(1);
    }
  }
  __builtin_amdgcn_wave_barrier();

  // ---- gather: 4 float4 per thread, consecutive threads -> consecutive f4 ----
  const int tid = blk * TPB + l;
#pragma unroll
  for (int k = 0; k < 4; ++k) {
    int t = tid + k * (GBLK * TPB);
    if (t < XQ) {
      const int perb = NSEL * 192;  // 768/4 float4s per patch
      int b = t / perb;
      int rem = t - b * perb;
      int n = rem / 192;
      int q = rem - n * 192;
      int d = q << 2;   // 0..764 step 4
      int c = d >> 8;   // channel 0..2
      int dd = d & 255;
      int pr = dd >> 4;
      int pc = dd & 15;
      int id = __hip_atomic_load(&idx[b * NSEL + n], __ATOMIC_RELAXED,
                                 __HIP_MEMORY_SCOPE_AGENT);
      int ri = (id >> 4) << 4, ci = (id & 15) << 4;
      out[t] = *reinterpret_cast<const float4*>(
          x + (((size_t)(b * C + c)) * H + ri + pr) * W + ci + pc);
    } else {
      int u = t - XQ;
      const int perb = NSEL * 128;  // 512/4 float4s per patch
      int b = u / perb;
      int rem = u - b * perb;
      int n = rem / 128;
      int q = rem - n * 128;
      int d = q << 2;
      int ch = d >> 8;  // first 2 channels of pos
      int dd = d & 255;
      int pr = dd >> 4;
      int pc = dd & 15;
      int id = __hip_atomic_load(&idx[b * NSEL + n], __ATOMIC_RELAXED,
                                 __HIP_MEMORY_SCOPE_AGENT);
      int ri = (id >> 4) << 4, ci = (id & 15) << 4;
      out[t] = *reinterpret_cast<const float4*>(
          pos + (((size_t)(b * 512 + ch)) * H + ri + pr) * W + ci + pc);
    }
  }
}

extern "C" void kernel_launch(void* const* d_in, const int* in_sizes, int n_in,
                              void* d_out, int out_size, void* d_ws, size_t ws_size,
                              hipStream_t stream) {
  const float* x = (const float*)d_in[0];     // [4,3,256,256]
  const float* mask = (const float*)d_in[1];  // [4,1,256,256]
  const float* pos = (const float*)d_in[2];   // [4,512,256,256]

  fused_kernel<<<GBLK, TPB, 0, stream>>>(x, mask, pos, (float4*)d_out,
                                         (int*)d_ws);
}

// Round 4
// 19.282 us; speedup vs baseline: 1.8815x; 1.8815x over previous
//
#include <hip/hip_runtime.h>

constexpr int PP = 16;       // patch
constexpr int NSEL = 128;    // N
constexpr int B = 4, C = 3, H = 256, W = 256;
constexpr int L = 256;       // patches per batch (16x16)
constexpr int TPB = 256;
constexpr int BLKS_PER_B = 40;               // 160 blocks total, 1 dispatch
constexpr int F4_PER_B_X = NSEL * 192;       // 24576 float4s (x part, per batch)
constexpr int F4_PER_B_P = NSEL * 128;       // 16384 float4s (pos part, per batch)
constexpr int F4_PER_B = F4_PER_B_X + F4_PER_B_P;  // 40960 = 40 blocks * 1024
constexpr int XQ = B * F4_PER_B_X;           // x_sample float4 count

__device__ __forceinline__ unsigned rotl32(unsigned x, int d) {
  return (x << d) | (x >> (32 - d));
}

// Threefry-2x32, 20 rounds (Random123 / JAX), key=(0,42), partitionable mode:
// counter=(0, i), bits = y0 ^ y1. Verified exact (absmax 0.0, rounds 1-3).
__device__ __forceinline__ void threefry2x32(unsigned k0, unsigned k1,
                                             unsigned& x0, unsigned& x1) {
  unsigned ks[3] = {k0, k1, k0 ^ k1 ^ 0x1BD11BDAu};
  x0 += ks[0];
  x1 += ks[1];
  const int rot[2][4] = {{13, 15, 26, 6}, {17, 29, 16, 24}};
#pragma unroll
  for (int i = 0; i < 5; ++i) {
    const int* r = rot[i & 1];
#pragma unroll
    for (int j = 0; j < 4; ++j) {
      x0 += x1;
      x1 = rotl32(x1, r[j]);
      x1 ^= x0;
    }
    x0 += ks[(i + 1) % 3];
    x1 += ks[(i + 2) % 3] + (unsigned)(i + 1);
  }
}

// Single dispatch, zero inter-block communication. 40 blocks per batch; each
// block redundantly computes its batch's selection (deterministic, verified
// logic from rounds 1-2), then gathers a 1024-float4 slice of the output.
// Out layout: x_sample [4,128,768] f32 then pos_sample [4,128,512] f32.
__global__ __launch_bounds__(TPB) void fused_kernel(
    const float* __restrict__ x, const float* __restrict__ mask,
    const float* __restrict__ pos, float4* __restrict__ out) {
  const int b = blockIdx.x / BLKS_PER_B;       // batch 0..3
  const int sub = blockIdx.x % BLKS_PER_B;     // slice 0..39 within batch
  const int l = threadIdx.x;                   // 0..255 == patch id

  // ---- selection for batch b (thread l owns patch l) ----
  int ri = (l >> 4) << 4, ci = (l & 15) << 4;
  const float* base = mask + ((size_t)b * H + ri) * W + ci;
  float s = 0.0f;
#pragma unroll
  for (int r = 0; r < PP; ++r) {
#pragma unroll
    for (int c4 = 0; c4 < 4; ++c4) {
      const float4 v = *reinterpret_cast<const float4*>(base + r * W + c4 * 4);
      s += v.x + v.y + v.z + v.w;
    }
  }
  bool valid = (s * (1.0f / 256.0f)) >= 1.0f;

  unsigned x0 = 0u, x1 = (unsigned)(b * L + l);
  threefry2x32(0u, 42u, x0, x1);
  unsigned score = valid ? (((x0 ^ x1) >> 9) + 1u) : 0u;

  __shared__ unsigned s_score[L];
  __shared__ int s_wcnt[4];
  __shared__ int s_idx[NSEL];
  s_score[l] = score;
  __syncthreads();

  int rank = 0;
  const uint4* sv = reinterpret_cast<const uint4*>(s_score);
#pragma unroll 8
  for (int m4 = 0; m4 < L / 4; ++m4) {
    uint4 v = sv[m4];
    int m = m4 << 2;
    rank += (v.x > score) || (v.x == score && (m + 0) < l);
    rank += (v.y > score) || (v.y == score && (m + 1) < l);
    rank += (v.z > score) || (v.z == score && (m + 2) < l);
    rank += (v.w > score) || (v.w == score && (m + 3) < l);
  }
  bool sel = rank < NSEL;

  unsigned long long mb = __ballot(sel);
  int w = l >> 6, ln = l & 63;
  if (ln == 0) s_wcnt[w] = __popcll(mb);
  __syncthreads();
  int slot = __popcll(mb & ((1ull << ln) - 1ull));
#pragma unroll
  for (int j = 0; j < 4; ++j) slot += (j < w) ? s_wcnt[j] : 0;
  if (sel) s_idx[slot] = l;   // ascending patch order == jnp.sort(top_k idx)
  __syncthreads();

  // ---- gather this block's slice: 4 float4s per thread ----
#pragma unroll
  for (int k = 0; k < 4; ++k) {
    int u = sub * (TPB * 4) + k * TPB + l;     // 0..40959 within batch
    if (u < F4_PER_B_X) {
      int n = u / 192;                         // sampled-patch slot
      int q = u - n * 192;
      int d = q << 2;                          // 0..764 step 4
      int c = d >> 8;                          // channel 0..2
      int dd = d & 255;
      int pr = dd >> 4;
      int pc = dd & 15;
      int id = s_idx[n];
      int pri = (id >> 4) << 4, pci = (id & 15) << 4;
      out[b * F4_PER_B_X + u] = *reinterpret_cast<const float4*>(
          x + (((size_t)(b * C + c)) * H + pri + pr) * W + pci + pc);
    } else {
      int v = u - F4_PER_B_X;                  // 0..16383
      int n = v >> 7;
      int q = v & 127;
      int d = q << 2;
      int ch = d >> 8;                         // first 2 channels of pos
      int dd = d & 255;
      int pr = dd >> 4;
      int pc = dd & 15;
      int id = s_idx[n];
      int pri = (id >> 4) << 4, pci = (id & 15) << 4;
      out[XQ + b * F4_PER_B_P + v] = *reinterpret_cast<const float4*>(
          pos + (((size_t)(b * 512 + ch)) * H + pri + pr) * W + pci + pc);
    }
  }
}

extern "C" void kernel_launch(void* const* d_in, const int* in_sizes, int n_in,
                              void* d_out, int out_size, void* d_ws, size_t ws_size,
                              hipStream_t stream) {
  const float* x = (const float*)d_in[0];     // [4,3,256,256]
  const float* mask = (const float*)d_in[1];  // [4,1,256,256]
  const float* pos = (const float*)d_in[2];   // [4,512,256,256]

  fused_kernel<<<B * BLKS_PER_B, TPB, 0, stream>>>(x, mask, pos,
                                                   (float4*)d_out);
}